// Round 11
// baseline (296.150 us; speedup 1.0000x reference)
//
#include <hip/hip_runtime.h>
#include <math.h>

typedef unsigned long long u64;

// ---------------------------------------------------------------------------
// Kernel 1: KNN (bit-exact vs np/fp32 reference) + fused 3-scale surface conv.
// (unchanged from round 10)
// ---------------------------------------------------------------------------
__global__ __launch_bounds__(256) void knnsurf_kernel(
    const float* __restrict__ verts,
    int* __restrict__ idx_out, float4* __restrict__ nd_out,
    const float* __restrict__ dl, const float* __restrict__ dm,
    const float* __restrict__ dg,
    float* __restrict__ raw_l, float* __restrict__ raw_m, float* __restrict__ raw_g)
{
    __shared__ float4 vps[1024];                    // x,y,z,sq  (16 KB)
    __shared__ __align__(16) u64 cand[4][208];      // 6.7 KB
    const int tid = threadIdx.x;
    const int row0 = blockIdx.x * 4;
    const int b = row0 >> 10;
    const float* vb = verts + b * 3072;

    for (int n = tid; n < 1024; n += 256) {
        float x = vb[3 * n], y = vb[3 * n + 1], z = vb[3 * n + 2];
        float s = __fadd_rn(__fadd_rn(__fmul_rn(x, x), __fmul_rn(y, y)),
                            __fmul_rn(z, z));
        vps[n] = make_float4(x, y, z, s);
    }
    __syncthreads();

    const int w = tid >> 6, lane = tid & 63;
    const int row = row0 + w;
    const int n_i = row & 1023;
    const float4 pi = vps[n_i];
    const float xi = pi.x, yi = pi.y, zi = pi.z, sqi = pi.w;

    u64 K[16];
    u64 m1 = ~0ULL, m2 = ~0ULL;
#pragma unroll
    for (int t = 0; t < 16; ++t) {
        int j = t * 64 + lane;
        float4 p = vps[j];
        float dot = __fadd_rn(__fadd_rn(__fmul_rn(xi, p.x),
                                        __fmul_rn(yi, p.y)),
                              __fmul_rn(zi, p.z));
        float d = __fsub_rn(__fadd_rn(sqi, p.w), __fmul_rn(2.0f, dot));
        d = __fadd_rn(d, 0.0f);
        unsigned u = __float_as_uint(d);
        unsigned m = (u & 0x80000000u) ? ~u : (u | 0x80000000u);
        u64 k = ((u64)m << 10) | (unsigned)j;
        K[t] = k;
        bool lt1 = k < m1;
        u64 nm2 = lt1 ? m1 : ((k < m2) ? k : m2);
        m1 = lt1 ? k : m1;
        m2 = nm2;
    }

    u64 tmax = m2, tmin = m1;
#pragma unroll
    for (int off = 1; off < 64; off <<= 1) {
        u64 a = __shfl_xor(tmax, off); if (a > tmax) tmax = a;
        u64 c = __shfl_xor(tmin, off); if (c < tmin) tmin = c;
    }

    u64 T = tmax;
    int chi;
    {
        int c = 0;
#pragma unroll
        for (int t = 0; t < 16; ++t) c += (K[t] < T) ? 1 : 0;
#pragma unroll
        for (int off = 1; off < 64; off <<= 1) c += __shfl_xor(c, off);
        chi = c;
    }
    u64 lo = tmin, hi = T;
    while (chi > 192) {
        u64 mid = (lo + hi) >> 1;
        int c = 0;
#pragma unroll
        for (int t = 0; t < 16; ++t) c += (K[t] < mid) ? 1 : 0;
#pragma unroll
        for (int off = 1; off < 64; off <<= 1) c += __shfl_xor(c, off);
        if (c >= 101) { hi = mid; chi = c; } else lo = mid;
    }
    T = hi;
    const int n = chi;

    int myc_n = 0;
#pragma unroll
    for (int t = 0; t < 16; ++t) myc_n += (K[t] < T) ? 1 : 0;
    int sc = myc_n;
#pragma unroll
    for (int off = 1; off < 64; off <<= 1) {
        int v = __shfl_up(sc, off);
        if (lane >= off) sc += v;
    }
    int pos = sc - myc_n;
#pragma unroll
    for (int t = 0; t < 16; ++t) {
        if (K[t] < T) cand[w][pos++] = K[t];
    }
    if (lane == 0) cand[w][n] = ~0ULL;
    __syncthreads();

    u64 myc[3]; int rk[3];
#pragma unroll
    for (int q = 0; q < 3; ++q) {
        int i = lane + q * 64;
        myc[q] = (i < n) ? cand[w][i] : ~0ULL;
        rk[q] = 0;
    }
    {
        const ulonglong2* c2 = (const ulonglong2*)&cand[w][0];
        const int half = (n + 1) >> 1;
        for (int jj = 0; jj < half; ++jj) {
            ulonglong2 kk = c2[jj];
#pragma unroll
            for (int q = 0; q < 3; ++q) {
                rk[q] += (kk.x < myc[q]) ? 1 : 0;
                rk[q] += (kk.y < myc[q]) ? 1 : 0;
            }
        }
    }

    const int rowbase = row & ~1023;
    float4* nd4w = (float4*)&cand[w][0];
#pragma unroll
    for (int q = 0; q < 3; ++q) {
        int i = lane + q * 64;
        if (i < n) {
            int r = rk[q];
            if (r >= 1 && r <= 100) {
                int slot = r - 1;
                unsigned j = (unsigned)(myc[q] & 1023u);
                idx_out[row * 100 + slot] = rowbase + (int)j;
                float4 pj = vps[j];
                float dx = pj.x - xi, dy = pj.y - yi, dz = pj.z - zi;
                float nrm = sqrtf(__fadd_rn(__fadd_rn(__fmul_rn(dx, dx),
                                                      __fmul_rn(dy, dy)),
                                            __fmul_rn(dz, dz)));
                float inv = 1.0f / fmaxf(nrm, 1e-12f);
                float4 nv = make_float4(dx * inv, dy * inv, dz * inv, 0.0f);
                nd_out[row * 100 + slot] = nv;
                nd4w[slot] = nv;
            }
        }
    }
    __syncthreads();

    const int d = tid & 127;
    float lx = dl[d], ly = dl[128 + d], lz = dl[256 + d];
    float li = 1.0f / fmaxf(sqrtf((lx * lx + ly * ly) + lz * lz), 1e-12f);
    lx *= li; ly *= li; lz *= li;
    float mx = dm[d], my = dm[128 + d], mz = dm[256 + d];
    float mi = 1.0f / fmaxf(sqrtf((mx * mx + my * my) + mz * mz), 1e-12f);
    mx *= mi; my *= mi; mz *= mi;
    float gx = dg[d], gy = dg[128 + d], gz = dg[256 + d];
    float gi = 1.0f / fmaxf(sqrtf((gx * gx + gy * gy) + gz * gz), 1e-12f);
    gx *= gi; gy *= gi; gz *= gi;

#pragma unroll
    for (int p = 0; p < 2; ++p) {
        int rr = (tid >> 7) + 2 * p;
        const float4* ns = (const float4*)&cand[rr][0];
        float ml = -1e30f, mm = -1e30f, mg = -1e30f;
        int k = 0;
        for (; k < 5; ++k) {
            float4 v = ns[k];
            ml = fmaxf(ml, (v.x * lx + v.y * ly) + v.z * lz);
            mm = fmaxf(mm, (v.x * mx + v.y * my) + v.z * mz);
            mg = fmaxf(mg, (v.x * gx + v.y * gy) + v.z * gz);
        }
        for (; k < 20; ++k) {
            float4 v = ns[k];
            mm = fmaxf(mm, (v.x * mx + v.y * my) + v.z * mz);
            mg = fmaxf(mg, (v.x * gx + v.y * gy) + v.z * gz);
        }
        for (; k < 100; ++k) {
            float4 v = ns[k];
            mg = fmaxf(mg, (v.x * gx + v.y * gy) + v.z * gz);
        }
        int orow = row0 + rr;
        raw_l[orow * 128 + d] = fmaxf(ml, 0.0f);
        raw_m[orow * 128 + d] = fmaxf(mm, 0.0f);
        raw_g[orow * 128 + d] = fmaxf(mg, 0.0f);
    }
}

// ---------------------------------------------------------------------------
// Kernel 2: BN partial sums: 32 blocks per tensor (fp64, deterministic).
// ---------------------------------------------------------------------------
__global__ __launch_bounds__(256) void bnsum_kernel(
    const float* s0, double* p0,
    const float* s1, double* p1,
    const float* s2, double* p2)
{
    const int t = blockIdx.x >> 5;
    const int blk = blockIdx.x & 31;
    const float* src = (t == 0) ? s0 : (t == 1) ? s1 : s2;
    double* p = (t == 0) ? p0 : (t == 1) ? p1 : p2;
    const int tid = threadIdx.x;
    const int c = tid & 127, seg = tid >> 7;
    const float* q = src + ((size_t)blk * 128 + seg * 64) * 128 + c;
    double s = 0.0, ss = 0.0;
    for (int r = 0; r < 64; ++r) { float v = q[r * 128]; s += v; ss += (double)v * v; }
    __shared__ double Ls[2][128], Lq[2][128];
    Ls[seg][c] = s; Lq[seg][c] = ss;
    __syncthreads();
    if (tid < 128) {
        p[blk * 256 + c]       = Ls[0][c] + Ls[1][c];
        p[blk * 256 + 128 + c] = Lq[0][c] + Lq[1][c];
    }
}

// st from partials: a = g/sqrt(var+eps), b2 = e - m*a (fp64, deterministic)
__device__ __forceinline__ void compute_st(const double* __restrict__ p,
                                           const float* __restrict__ g,
                                           const float* __restrict__ e,
                                           float* stA, float* stB,
                                           int tid, int nthreads)
{
    for (int c = tid; c < 128; c += nthreads) {
        double S = 0.0, Q = 0.0;
#pragma unroll
        for (int bb = 0; bb < 32; ++bb) { S += p[bb * 256 + c]; Q += p[bb * 256 + 128 + c]; }
        double m = S * (1.0 / 4096.0);
        double var = Q * (1.0 / 4096.0) - m * m;
        double a = (double)g[c] / sqrt(var + 1e-5);
        stA[c] = (float)a;
        stB[c] = (float)((double)e[c] - m * a);
    }
}

// ---------------------------------------------------------------------------
// Kernel 3: apply bn_relu -> global (so GEMMs read clean A with wave-uniform
// scalar loads). blockIdx.y = tensor, blockIdx.x = 64-row slab.
// ---------------------------------------------------------------------------
__global__ __launch_bounds__(256) void bnrelu_kernel(
    const float* s0, const double* p0, const float* g0, const float* e0, float* o0,
    const float* s1, const double* p1, const float* g1, const float* e1, float* o1,
    const float* s2, const double* p2, const float* g2, const float* e2, float* o2)
{
    const int t = blockIdx.y;
    const float* src = (t == 0) ? s0 : (t == 1) ? s1 : s2;
    const double* p = (t == 0) ? p0 : (t == 1) ? p1 : p2;
    const float* g = (t == 0) ? g0 : (t == 1) ? g1 : g2;
    const float* e = (t == 0) ? e0 : (t == 1) ? e1 : e2;
    float* dst = (t == 0) ? o0 : (t == 1) ? o1 : o2;

    __shared__ float stA[128], stB[128];
    const int tid = threadIdx.x;
    compute_st(p, g, e, stA, stB, tid, 256);
    __syncthreads();

    const size_t base4 = (size_t)blockIdx.x * 2048;   // 64 rows * 128 / 4
    const float4* s4 = (const float4*)src + base4;
    float4* d4 = (float4*)dst + base4;
    for (int i = tid; i < 2048; i += 256) {
        float4 v = s4[i];
        int c = (i & 31) * 4;
        v.x = fmaxf(fmaf(stA[c + 0], v.x, stB[c + 0]), 0.0f);
        v.y = fmaxf(fmaf(stA[c + 1], v.y, stB[c + 1]), 0.0f);
        v.z = fmaxf(fmaf(stA[c + 2], v.z, stB[c + 2]), 0.0f);
        v.w = fmaxf(fmaf(stA[c + 3], v.w, stB[c + 3]), 0.0f);
        d4[i] = v;
    }
}

// ---------------------------------------------------------------------------
// Kernel 4: dual-job GEMM (CIN=128), 8 rows/block. A is bn_relu'd global;
// A loads are wave-uniform (scalar pipe), W loads vector (VMEM), no LDS.
// ---------------------------------------------------------------------------
__global__ __launch_bounds__(256) void gemm2_kernel(
    const float* __restrict__ Aa, const float* __restrict__ Wa,
    const float* __restrict__ ba, float* __restrict__ outa,
    const float* __restrict__ Ab, const float* __restrict__ Wb,
    const float* __restrict__ bb, float* __restrict__ outb)
{
    const int job = blockIdx.y;
    const float* A = job ? Ab : Aa;  const float* W = job ? Wb : Wa;
    const float* bias = job ? bb : ba;
    float* out = job ? outb : outa;

    const int o = threadIdx.x;
    const int r0 = blockIdx.x * 8;
    const float* Ar = A + (size_t)r0 * 128;

    float acc[8];
    const float bz = bias[o];
#pragma unroll
    for (int r = 0; r < 8; ++r) acc[r] = bz;

    for (int c = 0; c < 128; c += 4) {
        float w0 = W[(c + 0) * 256 + o];
        float w1 = W[(c + 1) * 256 + o];
        float w2 = W[(c + 2) * 256 + o];
        float w3 = W[(c + 3) * 256 + o];
#pragma unroll
        for (int r = 0; r < 8; ++r) {
            const float4 av = *(const float4*)(Ar + r * 128 + c);   // uniform
            acc[r] += av.x * w0 + av.y * w1 + av.z * w2 + av.w * w3;
        }
    }
#pragma unroll
    for (int r = 0; r < 8; ++r)
        out[(r0 + r) * 256 + o] = acc[r];
}

// ---------------------------------------------------------------------------
// Kernel 5: conv-layer apply (unchanged).
// ---------------------------------------------------------------------------
__global__ __launch_bounds__(128) void layer_kernel(
    const float4* __restrict__ nd, const int* __restrict__ idxbuf,
    const float* dir0, const float* fo0, float* out0, int K0,
    const float* dir1, const float* fo1, float* out1, int K1)
{
    const int job = blockIdx.y;
    const float* dirs = job ? dir1 : dir0;
    const float* fo = job ? fo1 : fo0;
    float* out = job ? out1 : out0;
    const int K = job ? K1 : K0;

    const int d = threadIdx.x;
    const int row = blockIdx.x;

    float dx = dirs[d], dy = dirs[128 + d], dz = dirs[256 + d];
    float di = 1.0f / fmaxf(sqrtf((dx * dx + dy * dy) + dz * dz), 1e-12f);
    dx *= di; dy *= di; dz *= di;

    const float4* ns = nd + (size_t)row * 100;
    const int* ib = idxbuf + (size_t)row * 100;

    float acc = -1e30f;
    for (int k = 0; k < K; ++k) {
        float4 v = ns[k];
        int ix = ib[k];
        float th = fmaxf((v.x * dx + v.y * dy) + v.z * dz, 0.0f);
        float fs = fo[ix * 256 + 128 + d];
        acc = fmaxf(acc, th * fs);
    }
    out[row * 128 + d] = fo[row * 256 + d] + acc;
}

// ---------------------------------------------------------------------------
// Kernel 6: final GEMM (CIN=384 from 3 bn_relu'd tensors), 8 rows/block,
// uniform A loads, final relu, fp32 out. No LDS.
// ---------------------------------------------------------------------------
__global__ __launch_bounds__(256) void gemmf_kernel(
    const float* __restrict__ A0, const float* __restrict__ A1,
    const float* __restrict__ A2,
    const float* __restrict__ W, const float* __restrict__ bias,
    float* __restrict__ out)
{
    const int o = threadIdx.x;
    const int r0 = blockIdx.x * 8;

    float acc[8];
    const float bz = bias[o];
#pragma unroll
    for (int r = 0; r < 8; ++r) acc[r] = bz;

#pragma unroll
    for (int seg = 0; seg < 3; ++seg) {
        const float* A = (seg == 0) ? A0 : (seg == 1) ? A1 : A2;
        const float* Ar = A + (size_t)r0 * 128;
        const float* Ws = W + (size_t)seg * 128 * 256;
        for (int c = 0; c < 128; c += 4) {
            float w0 = Ws[(c + 0) * 256 + o];
            float w1 = Ws[(c + 1) * 256 + o];
            float w2 = Ws[(c + 2) * 256 + o];
            float w3 = Ws[(c + 3) * 256 + o];
#pragma unroll
            for (int r = 0; r < 8; ++r) {
                const float4 av = *(const float4*)(Ar + r * 128 + c); // uniform
                acc[r] += av.x * w0 + av.y * w1 + av.z * w2 + av.w * w3;
            }
        }
    }
#pragma unroll
    for (int r = 0; r < 8; ++r)
        out[(r0 + r) * 256 + o] = fmaxf(acc[r], 0.0f);
}

// ---------------------------------------------------------------------------
extern "C" void kernel_launch(void* const* d_in, const int* in_sizes, int n_in,
                              void* d_out, int out_size, void* d_ws, size_t ws_size,
                              hipStream_t stream)
{
    (void)in_sizes; (void)n_in; (void)out_size; (void)ws_size;

    const float* verts   = (const float*)d_in[0];
    const float* dirs_l  = (const float*)d_in[1];
    const float* dirs_m0 = (const float*)d_in[2];
    const float* W_m1    = (const float*)d_in[3];
    const float* b_m1    = (const float*)d_in[4];
    const float* dirs_m1 = (const float*)d_in[5];
    const float* dirs_g0 = (const float*)d_in[6];
    const float* W_g1    = (const float*)d_in[7];
    const float* b_g1    = (const float*)d_in[8];
    const float* dirs_g1 = (const float*)d_in[9];
    const float* W_g2    = (const float*)d_in[10];
    const float* b_g2    = (const float*)d_in[11];
    const float* dirs_g2 = (const float*)d_in[12];
    const float* g_l  = (const float*)d_in[13]; const float* be_l  = (const float*)d_in[14];
    const float* g_m0 = (const float*)d_in[15]; const float* be_m0 = (const float*)d_in[16];
    const float* g_m1 = (const float*)d_in[17]; const float* be_m1 = (const float*)d_in[18];
    const float* g_g0 = (const float*)d_in[19]; const float* be_g0 = (const float*)d_in[20];
    const float* g_g1 = (const float*)d_in[21]; const float* be_g1 = (const float*)d_in[22];
    const float* g_g2 = (const float*)d_in[23]; const float* be_g2 = (const float*)d_in[24];
    const float* W_down = (const float*)d_in[25];
    const float* b_down = (const float*)d_in[26];

    char* ws = (char*)d_ws;
    const size_t MB = 1 << 20;
    int*    idx100 = (int*)   (ws + 0);               // 1.64 MB
    double* p_l    = (double*)(ws + 0x1A0000);        // 6 x 64 KB fp64 partials
    double* p_m0   = p_l  + 8192;
    double* p_m1   = p_m0 + 8192;
    double* p_g0   = p_m1 + 8192;
    double* p_g1   = p_g0 + 8192;
    double* p_g2   = p_g1 + 8192;
    float4* nd100  = (float4*)(ws + 2 * MB);          // 6.55 MB (stride-4)
    float* raw_l  = (float*)(ws +  9 * MB);           // 2 MB each
    float* raw_m0 = (float*)(ws + 11 * MB);
    float* raw_g0 = (float*)(ws + 13 * MB);
    float* raw_m1 = (float*)(ws + 15 * MB);
    float* raw_g1 = (float*)(ws + 17 * MB);
    float* raw_g2 = (float*)(ws + 19 * MB);
    float* fo_m   = (float*)(ws + 21 * MB);           // 4 MB each
    float* fo_g   = (float*)(ws + 25 * MB);
    float* fo_g2  = (float*)(ws + 29 * MB);
    float* abn_l  = (float*)(ws + 33 * MB);           // bn_relu'd, 2 MB each
    float* abn_m0 = (float*)(ws + 35 * MB);
    float* abn_g0 = (float*)(ws + 37 * MB);
    float* abn_m1 = (float*)(ws + 39 * MB);
    float* abn_g1 = (float*)(ws + 41 * MB);
    float* abn_g2 = (float*)(ws + 43 * MB);

    // L1. KNN + nd + fused surface convs
    knnsurf_kernel<<<1024, 256, 0, stream>>>(verts, idx100, nd100,
                                             dirs_l, dirs_m0, dirs_g0,
                                             raw_l, raw_m0, raw_g0);
    // L2. BN partials for l, m0, g0
    bnsum_kernel<<<96, 256, 0, stream>>>(raw_l, p_l, raw_m0, p_m0, raw_g0, p_g0);
    // L2b. apply bn_relu -> abn_{l,m0,g0}
    bnrelu_kernel<<<dim3(64, 3), 256, 0, stream>>>(
        raw_l,  p_l,  g_l,  be_l,  abn_l,
        raw_m0, p_m0, g_m0, be_m0, abn_m0,
        raw_g0, p_g0, g_g0, be_g0, abn_g0);
    // L3. fo_m = abn_m0 @ W_m1 ; fo_g = abn_g0 @ W_g1
    gemm2_kernel<<<dim3(512, 2), 256, 0, stream>>>(
        abn_m0, W_m1, b_m1, fo_m,
        abn_g0, W_g1, b_g1, fo_g);
    // L4. conv-layer apply (m1: K=20, g1: K=100)
    layer_kernel<<<dim3(4096, 2), 128, 0, stream>>>(nd100, idx100,
                                                    dirs_m1, fo_m, raw_m1, 20,
                                                    dirs_g1, fo_g, raw_g1, 100);
    // L5. BN partials for m1, g1
    bnsum_kernel<<<64, 256, 0, stream>>>(raw_m1, p_m1, raw_g1, p_g1, raw_g1, p_g1);
    // L5b. apply bn_relu -> abn_{m1,g1}
    bnrelu_kernel<<<dim3(64, 2), 256, 0, stream>>>(
        raw_m1, p_m1, g_m1, be_m1, abn_m1,
        raw_g1, p_g1, g_g1, be_g1, abn_g1,
        raw_g1, p_g1, g_g1, be_g1, abn_g1);
    // L6. fo_g2 = abn_g1 @ W_g2
    gemm2_kernel<<<dim3(512, 1), 256, 0, stream>>>(
        abn_g1, W_g2, b_g2, fo_g2,
        abn_g1, W_g2, b_g2, fo_g2);
    // L7. conv-layer apply (g2: K=100)
    layer_kernel<<<dim3(4096, 1), 128, 0, stream>>>(nd100, idx100,
                                                    dirs_g2, fo_g2, raw_g2, 100,
                                                    dirs_g2, fo_g2, raw_g2, 100);
    // L8. BN partials for g2
    bnsum_kernel<<<32, 256, 0, stream>>>(raw_g2, p_g2, raw_g2, p_g2, raw_g2, p_g2);
    // L8b. apply bn_relu -> abn_g2
    bnrelu_kernel<<<dim3(64, 1), 256, 0, stream>>>(
        raw_g2, p_g2, g_g2, be_g2, abn_g2,
        raw_g2, p_g2, g_g2, be_g2, abn_g2,
        raw_g2, p_g2, g_g2, be_g2, abn_g2);
    // L9. final: relu(concat @ W_down + b_down) -> fp32 out
    gemmf_kernel<<<512, 256, 0, stream>>>(abn_l, abn_m1, abn_g2,
                                          W_down, b_down, (float*)d_out);
}